// Round 14
// baseline (141.597 us; speedup 1.0000x reference)
//
#include <hip/hip_runtime.h>
#include <math.h>

#define N 2048
#define F 128
#define O 128
#define E 16

typedef __attribute__((ext_vector_type(8))) short          shortx8;
typedef __attribute__((ext_vector_type(8))) unsigned short u16x8;
typedef __attribute__((ext_vector_type(4))) unsigned short u16x4;
typedef __attribute__((ext_vector_type(4))) float          floatx4;

static __device__ __forceinline__ unsigned short f2bf(float f) {
    unsigned int u = __float_as_uint(f);
    unsigned int r = (u + 0x7FFFu + ((u >> 16) & 1u)) >> 16;
    return (unsigned short)r;
}

// ---------------- Kernel 1: preT[b][o][n] = (x @ w_b)[n][o] via MFMA ----------------
__global__ __launch_bounds__(256)
void pre_t(const float* __restrict__ x,
           const float* __restrict__ w0,
           const float* __restrict__ w1,
           unsigned short* __restrict__ preT) {
    __shared__ unsigned short wT[128 * 136];   // w^T bf16, padded stride 136
    const int t  = threadIdx.x;
    const int n0 = blockIdx.x * 16;
    const int b  = blockIdx.y;
    const float* __restrict__ wsrc = b ? w1 : w0;

#pragma unroll
    for (int i = 0; i < 64; ++i) {
        const int idx = i * 256 + t;          // coalesced read of w[k][o]
        const int k = idx >> 7, o = idx & 127;
        wT[o * 136 + k] = f2bf(wsrc[idx]);
    }
    __syncthreads();

    const int lane = t & 63;
    const int wv   = t >> 6;        // 0..3: 32-col group
    const int row  = lane & 15;
    const int kg   = lane >> 4;
    const int col0 = wv * 32 + row;

    floatx4 acc0 = {0.f, 0.f, 0.f, 0.f};
    floatx4 acc1 = {0.f, 0.f, 0.f, 0.f};

#pragma unroll
    for (int kk = 0; kk < 4; ++kk) {
        const float* xp = x + (size_t)(n0 + row) * F + kk * 32 + kg * 8;
        const float4 f0 = *(const float4*)(xp);
        const float4 f1 = *(const float4*)(xp + 4);
        shortx8 a;
        a[0] = (short)f2bf(f0.x); a[1] = (short)f2bf(f0.y);
        a[2] = (short)f2bf(f0.z); a[3] = (short)f2bf(f0.w);
        a[4] = (short)f2bf(f1.x); a[5] = (short)f2bf(f1.y);
        a[6] = (short)f2bf(f1.z); a[7] = (short)f2bf(f1.w);
        const shortx8 bA = *(const shortx8*)(wT + col0 * 136 + kk * 32 + kg * 8);
        const shortx8 bB = *(const shortx8*)(wT + (col0 + 16) * 136 + kk * 32 + kg * 8);
        acc0 = __builtin_amdgcn_mfma_f32_16x16x32_bf16(a, bA, acc0, 0, 0, 0);
        acc1 = __builtin_amdgcn_mfma_f32_16x16x32_bf16(a, bB, acc1, 0, 0, 0);
    }

    const int prow = kg * 4;
    u16x4 s0, s1;
#pragma unroll
    for (int j = 0; j < 4; ++j) { s0[j] = f2bf(acc0[j]); s1[j] = f2bf(acc1[j]); }
    *(u16x4*)(preT + ((size_t)b * O + col0) * N + n0 + prow)      = s0;
    *(u16x4*)(preT + ((size_t)b * O + col0 + 16) * N + n0 + prow) = s1;
}

// ---------------- Kernel 2: gate (R10-form: 4 lanes/pair, 65536 blocks) -------------
__global__ __launch_bounds__(256)
void gate_kernel(const float* __restrict__ ef,
                 const float* __restrict__ we,
                 const float* __restrict__ be,
                 const float* __restrict__ sup1,
                 unsigned short* __restrict__ G) {
    const size_t tid  = (size_t)blockIdx.x * 256 + threadIdx.x;
    const size_t pair = tid >> 2;
    const int    sub  = (int)(threadIdx.x & 3);
    const float4 e4 = ((const float4*)ef)[pair * 4 + sub];
    const float4 w4 = ((const float4*)we)[pair * 4 + sub];
    float v = e4.x * w4.x + e4.y * w4.y + e4.z * w4.z + e4.w * w4.w;
    v += __shfl_xor(v, 1);
    v += __shfl_xor(v, 2);
    if (sub == 0) {
        const float t = v + be[pair];
        const float g = (1.f / (1.f + __expf(-t))) * sup1[pair];
        G[pair] = f2bf(g);
    }
}

// ---------------- Kernel 3: dual GEMM, block split-K, full-unroll wave K=128 --------
// grid 2048 = 128 rb x 4 cg x 4 kc (XCD-chunked: each XCD owns 16 rb's entirely).
// 256 thr / 4 waves; wave wv covers K in [kc*512 + wv*128, +128): 4 steps, ALL
// 28 loads issued upfront -> one latency exposure; LDS 4-way reduce -> partial[kc].
__global__ __launch_bounds__(256, 3)
void gemm_partial(const float* __restrict__ S0,
                  const unsigned short* __restrict__ G,
                  const unsigned short* __restrict__ preT,
                  float* __restrict__ partial) {
    __shared__ float red[4][16][36];

    const int bx   = blockIdx.x;
    const int orig = (bx & 7) * 256 + (bx >> 3);  // XCD x -> orig [x*256, x*256+256)
    const int rb   = orig >> 4;                   // 0..127 (16 per XCD)
    const int cg   = (orig >> 2) & 3;             // 0..3
    const int kc   = orig & 3;                    // 0..3
    const int n0   = rb * 16;

    const int t    = threadIdx.x;
    const int lane = t & 63;
    const int wv   = t >> 6;                      // 0..3
    const int m_b  = kc * 512 + wv * 128;
    const int row  = lane & 15;
    const int kg   = lane >> 4;
    const int col0 = cg * 32 + row;

    const float*          aS = S0   + (size_t)(n0 + row) * N + m_b + kg * 8;
    const unsigned short* aG = G    + (size_t)(n0 + row) * N + m_b + kg * 8;
    const unsigned short* b0 = preT + (size_t)col0 * N        + m_b + kg * 8;
    const unsigned short* b1 = b0 + (size_t)16 * N;
    const unsigned short* c0 = b0 + (size_t)O * N;   // preT[1]
    const unsigned short* c1 = b1 + (size_t)O * N;

    // issue ALL loads upfront (compile-time indices -> registers)
    float4  Af0[4], Af1[4];
    shortx8 Ag[4], B00[4], B01[4], B10[4], B11[4];
#pragma unroll
    for (int s = 0; s < 4; ++s) {
        const int mo = s * 32;
        Af0[s] = *(const float4*)(aS + mo);
        Af1[s] = *(const float4*)(aS + mo + 4);
        Ag[s]  = *(const shortx8*)(aG + mo);
        B00[s] = *(const shortx8*)(b0 + mo);
        B01[s] = *(const shortx8*)(b1 + mo);
        B10[s] = *(const shortx8*)(c0 + mo);
        B11[s] = *(const shortx8*)(c1 + mo);
    }

    floatx4 acc0 = {0.f, 0.f, 0.f, 0.f};
    floatx4 acc1 = {0.f, 0.f, 0.f, 0.f};
#pragma unroll
    for (int s = 0; s < 4; ++s) {
        shortx8 a_s;
        a_s[0] = (short)f2bf(Af0[s].x); a_s[1] = (short)f2bf(Af0[s].y);
        a_s[2] = (short)f2bf(Af0[s].z); a_s[3] = (short)f2bf(Af0[s].w);
        a_s[4] = (short)f2bf(Af1[s].x); a_s[5] = (short)f2bf(Af1[s].y);
        a_s[6] = (short)f2bf(Af1[s].z); a_s[7] = (short)f2bf(Af1[s].w);
        acc0 = __builtin_amdgcn_mfma_f32_16x16x32_bf16(a_s,   B00[s], acc0, 0, 0, 0);
        acc0 = __builtin_amdgcn_mfma_f32_16x16x32_bf16(Ag[s], B10[s], acc0, 0, 0, 0);
        acc1 = __builtin_amdgcn_mfma_f32_16x16x32_bf16(a_s,   B01[s], acc1, 0, 0, 0);
        acc1 = __builtin_amdgcn_mfma_f32_16x16x32_bf16(Ag[s], B11[s], acc1, 0, 0, 0);
    }

    // stash per-wave acc in LDS: C/D col = lane&15, row = kg*4 + j
    const int prow = kg * 4;
#pragma unroll
    for (int j = 0; j < 4; ++j) {
        red[wv][prow + j][row]      = acc0[j];
        red[wv][prow + j][16 + row] = acc1[j];
    }
    __syncthreads();

    // 256 threads: one row r, two cols c,c+1; sum over 4 waves -> partial[kc]
    {
        const int r = t >> 4;
        const int c = (t & 15) * 2;
        float v0 = red[0][r][c]     + red[1][r][c]     + red[2][r][c]     + red[3][r][c];
        float v1 = red[0][r][c + 1] + red[1][r][c + 1] + red[2][r][c + 1] + red[3][r][c + 1];
        float2 o2; o2.x = v0; o2.y = v1;
        *(float2*)(partial + (size_t)kc * (N * O)
                   + (size_t)(n0 + r) * O + cg * 32 + c) = o2;
    }
}

// ---------------- Kernel 4: out = relu(sum_kc partial + bias) -----------------------
__global__ __launch_bounds__(256)
void reduce_out(const float* __restrict__ partial,
                const float* __restrict__ bias,
                float* __restrict__ out) {
    const int i4 = blockIdx.x * 256 + threadIdx.x;   // float4 index over [N][O]
    const float4* p = (const float4*)partial;
    const float4 a = p[i4];
    const float4 b = p[i4 + 65536];
    const float4 c = p[i4 + 2 * 65536];
    const float4 d = p[i4 + 3 * 65536];
    const float4 bb = ((const float4*)bias)[i4 & 31];
    float4 r;
    r.x = fmaxf(a.x + b.x + c.x + d.x + bb.x, 0.f);
    r.y = fmaxf(a.y + b.y + c.y + d.y + bb.y, 0.f);
    r.z = fmaxf(a.z + b.z + c.z + d.z + bb.z, 0.f);
    r.w = fmaxf(a.w + b.w + c.w + d.w + bb.w, 0.f);
    ((float4*)out)[i4] = r;
}

extern "C" void kernel_launch(void* const* d_in, const int* in_sizes, int n_in,
                              void* d_out, int out_size, void* d_ws, size_t ws_size,
                              hipStream_t stream) {
    const float* x   = (const float*)d_in[0];   // [N,F]
    const float* sup = (const float*)d_in[1];   // [2,N,N]
    const float* ef  = (const float*)d_in[2];   // [N,N,E]
    const float* we  = (const float*)d_in[3];   // [N,N,E]
    const float* be  = (const float*)d_in[4];   // [N,N]
    const float* w0  = (const float*)d_in[5];   // [F,O]
    const float* w1  = (const float*)d_in[6];   // [F,O]
    const float* b   = (const float*)d_in[7];   // [O]
    float* out = (float*)d_out;

    unsigned short* preT   = (unsigned short*)d_ws;      // [2][O][N] bf16, 1 MB
    unsigned short* G      = preT + 2 * (size_t)N * O;   // [N][N]   bf16, 8.4 MB
    float*          partial = (float*)(G + (size_t)N * N); // [4][N][O] f32, 4 MB

    pre_t<<<dim3(N / 16, 2), 256, 0, stream>>>(x, w0, w1, preT);
    gate_kernel<<<(unsigned)((size_t)N * N * 4 / 256), 256, 0, stream>>>(
        ef, we, be, sup + (size_t)N * N, G);
    gemm_partial<<<2048, 256, 0, stream>>>(sup, G, preT, partial);
    reduce_out<<<N * O / 4 / 256, 256, 0, stream>>>(partial, b, out);
}

// Round 15
// 138.612 us; speedup vs baseline: 1.0215x; 1.0215x over previous
//
#include <hip/hip_runtime.h>
#include <math.h>

#define N 2048
#define F 128
#define O 128
#define E 16

typedef __attribute__((ext_vector_type(8))) short          shortx8;
typedef __attribute__((ext_vector_type(8))) unsigned short u16x8;
typedef __attribute__((ext_vector_type(4))) unsigned short u16x4;
typedef __attribute__((ext_vector_type(4))) float          floatx4;

static __device__ __forceinline__ unsigned short f2bf(float f) {
    unsigned int u = __float_as_uint(f);
    unsigned int r = (u + 0x7FFFu + ((u >> 16) & 1u)) >> 16;
    return (unsigned short)r;
}

// ---------------- Kernel 1: preT[b][o][n] = (x @ w_b)[n][o] via MFMA ----------------
__global__ __launch_bounds__(256)
void pre_t(const float* __restrict__ x,
           const float* __restrict__ w0,
           const float* __restrict__ w1,
           unsigned short* __restrict__ preT) {
    __shared__ unsigned short wT[128 * 136];   // w^T bf16, padded stride 136
    const int t  = threadIdx.x;
    const int n0 = blockIdx.x * 16;
    const int b  = blockIdx.y;
    const float* __restrict__ wsrc = b ? w1 : w0;

#pragma unroll
    for (int i = 0; i < 64; ++i) {
        const int idx = i * 256 + t;          // coalesced read of w[k][o]
        const int k = idx >> 7, o = idx & 127;
        wT[o * 136 + k] = f2bf(wsrc[idx]);
    }
    __syncthreads();

    const int lane = t & 63;
    const int wv   = t >> 6;        // 0..3: 32-col group
    const int row  = lane & 15;
    const int kg   = lane >> 4;
    const int col0 = wv * 32 + row;

    floatx4 acc0 = {0.f, 0.f, 0.f, 0.f};
    floatx4 acc1 = {0.f, 0.f, 0.f, 0.f};

#pragma unroll
    for (int kk = 0; kk < 4; ++kk) {
        const float* xp = x + (size_t)(n0 + row) * F + kk * 32 + kg * 8;
        const float4 f0 = *(const float4*)(xp);
        const float4 f1 = *(const float4*)(xp + 4);
        shortx8 a;
        a[0] = (short)f2bf(f0.x); a[1] = (short)f2bf(f0.y);
        a[2] = (short)f2bf(f0.z); a[3] = (short)f2bf(f0.w);
        a[4] = (short)f2bf(f1.x); a[5] = (short)f2bf(f1.y);
        a[6] = (short)f2bf(f1.z); a[7] = (short)f2bf(f1.w);
        const shortx8 bA = *(const shortx8*)(wT + col0 * 136 + kk * 32 + kg * 8);
        const shortx8 bB = *(const shortx8*)(wT + (col0 + 16) * 136 + kk * 32 + kg * 8);
        acc0 = __builtin_amdgcn_mfma_f32_16x16x32_bf16(a, bA, acc0, 0, 0, 0);
        acc1 = __builtin_amdgcn_mfma_f32_16x16x32_bf16(a, bB, acc1, 0, 0, 0);
    }

    const int prow = kg * 4;
    u16x4 s0, s1;
#pragma unroll
    for (int j = 0; j < 4; ++j) { s0[j] = f2bf(acc0[j]); s1[j] = f2bf(acc1[j]); }
    *(u16x4*)(preT + ((size_t)b * O + col0) * N + n0 + prow)      = s0;
    *(u16x4*)(preT + ((size_t)b * O + col0 + 16) * N + n0 + prow) = s1;
}

// ---------------- Kernel 2: FUSED gate + S0-GEMM via block specialization -----------
// blocks 0..511:   S0-branch GEMM (4 waves, wave K=512) -> partial0  (no bias/relu)
// blocks 512..66047: R10-form gate -> G
// The s0 blocks run in the gate's shadow (gate is BW-bound, VALU/MFMA idle).
#define S0_BLOCKS 512

__global__ __launch_bounds__(256)
void gate_s0(const float* __restrict__ ef,
             const float* __restrict__ we,
             const float* __restrict__ be,
             const float* __restrict__ sup,      // [2][N][N]
             const unsigned short* __restrict__ preT,
             unsigned short* __restrict__ G,
             float* __restrict__ partial0) {
    __shared__ float red[4][16][36];
    const int bx = blockIdx.x;
    const int t  = threadIdx.x;

    if (bx < S0_BLOCKS) {
        // ---- S0-only GEMM: out_rows [rb*16, +16), cols [cg*32, +32) ----
        const int rb   = bx >> 2;
        const int cg   = bx & 3;
        const int n0   = rb * 16;
        const int lane = t & 63;
        const int wv   = t >> 6;            // 0..3
        const int m_b  = wv * 512;
        const int row  = lane & 15;
        const int kg   = lane >> 4;
        const int col0 = cg * 32 + row;

        const float*          aS = sup  + (size_t)(n0 + row) * N + m_b + kg * 8;
        const unsigned short* b0 = preT + (size_t)col0 * N       + m_b + kg * 8;
        const unsigned short* b1 = b0 + (size_t)16 * N;

        floatx4 acc0 = {0.f, 0.f, 0.f, 0.f};
        floatx4 acc1 = {0.f, 0.f, 0.f, 0.f};

#pragma unroll 2
        for (int s = 0; s < 16; ++s) {
            const int mo = s * 32;
            const float4 f0 = *(const float4*)(aS + mo);
            const float4 f1 = *(const float4*)(aS + mo + 4);
            const shortx8 b00 = *(const shortx8*)(b0 + mo);
            const shortx8 b01 = *(const shortx8*)(b1 + mo);
            shortx8 a_s;
            a_s[0] = (short)f2bf(f0.x); a_s[1] = (short)f2bf(f0.y);
            a_s[2] = (short)f2bf(f0.z); a_s[3] = (short)f2bf(f0.w);
            a_s[4] = (short)f2bf(f1.x); a_s[5] = (short)f2bf(f1.y);
            a_s[6] = (short)f2bf(f1.z); a_s[7] = (short)f2bf(f1.w);
            acc0 = __builtin_amdgcn_mfma_f32_16x16x32_bf16(a_s, b00, acc0, 0, 0, 0);
            acc1 = __builtin_amdgcn_mfma_f32_16x16x32_bf16(a_s, b01, acc1, 0, 0, 0);
        }

        const int prow = kg * 4;
#pragma unroll
        for (int j = 0; j < 4; ++j) {
            red[wv][prow + j][row]      = acc0[j];
            red[wv][prow + j][16 + row] = acc1[j];
        }
        __syncthreads();

        const int r = t >> 4;
        const int c = (t & 15) * 2;
        float v0 = red[0][r][c]     + red[1][r][c]     + red[2][r][c]     + red[3][r][c];
        float v1 = red[0][r][c + 1] + red[1][r][c + 1] + red[2][r][c + 1] + red[3][r][c + 1];
        float2 o2; o2.x = v0; o2.y = v1;
        *(float2*)(partial0 + (size_t)(n0 + r) * O + cg * 32 + c) = o2;
    } else {
        // ---- gate (R10 form): 4 lanes per pair ----
        const float* __restrict__ sup1 = sup + (size_t)N * N;
        const size_t tid  = (size_t)(bx - S0_BLOCKS) * 256 + t;
        const size_t pair = tid >> 2;
        const int    sub  = t & 3;
        const float4 e4 = ((const float4*)ef)[pair * 4 + sub];
        const float4 w4 = ((const float4*)we)[pair * 4 + sub];
        float v = e4.x * w4.x + e4.y * w4.y + e4.z * w4.z + e4.w * w4.w;
        v += __shfl_xor(v, 1);
        v += __shfl_xor(v, 2);
        if (sub == 0) {
            const float tt = v + be[pair];
            const float g  = (1.f / (1.f + __expf(-tt))) * sup1[pair];
            G[pair] = f2bf(g);
        }
    }
}

// ---------------- Kernel 3: G-branch GEMM + partial0 + bias + relu -> out -----------
// grid 512 (XCD-swizzled), 512 thr / 8 waves; wave wv: K in [wv*256, +256).
__global__ __launch_bounds__(512, 4)
void gemm_g_out(const unsigned short* __restrict__ G,
                const unsigned short* __restrict__ preT,
                const float* __restrict__ partial0,
                const float* __restrict__ bias,
                float* __restrict__ out) {
    __shared__ float red[8][16][36];

    const int bx   = blockIdx.x;
    const int orig = (bx & 7) * 64 + (bx >> 3);  // group 4 col-blocks per XCD
    const int rb   = orig >> 2;                  // 0..127
    const int cg   = orig & 3;                   // 0..3
    const int n0   = rb * 16;

    const int t    = threadIdx.x;
    const int lane = t & 63;
    const int wv   = t >> 6;                     // 0..7
    const int m_b  = wv * 256;
    const int row  = lane & 15;
    const int kg   = lane >> 4;
    const int col0 = cg * 32 + row;

    const unsigned short* aG = G    + (size_t)(n0 + row) * N      + m_b + kg * 8;
    const unsigned short* c0 = preT + (size_t)(O + col0) * N      + m_b + kg * 8;  // preT[1]
    const unsigned short* c1 = c0 + (size_t)16 * N;

    floatx4 acc0 = {0.f, 0.f, 0.f, 0.f};
    floatx4 acc1 = {0.f, 0.f, 0.f, 0.f};

#pragma unroll 2
    for (int s = 0; s < 8; ++s) {
        const int mo = s * 32;
        const shortx8 a_g = *(const shortx8*)(aG + mo);
        const shortx8 b10 = *(const shortx8*)(c0 + mo);
        const shortx8 b11 = *(const shortx8*)(c1 + mo);
        acc0 = __builtin_amdgcn_mfma_f32_16x16x32_bf16(a_g, b10, acc0, 0, 0, 0);
        acc1 = __builtin_amdgcn_mfma_f32_16x16x32_bf16(a_g, b11, acc1, 0, 0, 0);
    }

    const int prow = kg * 4;
#pragma unroll
    for (int j = 0; j < 4; ++j) {
        red[wv][prow + j][row]      = acc0[j];
        red[wv][prow + j][16 + row] = acc1[j];
    }
    __syncthreads();

    if (t < 256) {
        const int r = t >> 4;
        const int c = (t & 15) * 2;
        float v0 = 0.f, v1 = 0.f;
#pragma unroll
        for (int w = 0; w < 8; ++w) {
            v0 += red[w][r][c];
            v1 += red[w][r][c + 1];
        }
        const float2 p0 = *(const float2*)(partial0 + (size_t)(n0 + r) * O + cg * 32 + c);
        v0 = fmaxf(v0 + p0.x + bias[cg * 32 + c],     0.f);
        v1 = fmaxf(v1 + p0.y + bias[cg * 32 + c + 1], 0.f);
        float2 o2; o2.x = v0; o2.y = v1;
        *(float2*)(out + (size_t)(n0 + r) * O + cg * 32 + c) = o2;
    }
}

extern "C" void kernel_launch(void* const* d_in, const int* in_sizes, int n_in,
                              void* d_out, int out_size, void* d_ws, size_t ws_size,
                              hipStream_t stream) {
    const float* x   = (const float*)d_in[0];   // [N,F]
    const float* sup = (const float*)d_in[1];   // [2,N,N]
    const float* ef  = (const float*)d_in[2];   // [N,N,E]
    const float* we  = (const float*)d_in[3];   // [N,N,E]
    const float* be  = (const float*)d_in[4];   // [N,N]
    const float* w0  = (const float*)d_in[5];   // [F,O]
    const float* w1  = (const float*)d_in[6];   // [F,O]
    const float* b   = (const float*)d_in[7];   // [O]
    float* out = (float*)d_out;

    unsigned short* preT     = (unsigned short*)d_ws;      // [2][O][N] bf16, 1 MB
    unsigned short* G        = preT + 2 * (size_t)N * O;   // [N][N]   bf16, 8.4 MB
    float*          partial0 = (float*)(G + (size_t)N * N); // [N][O]  f32,  1 MB

    pre_t<<<dim3(N / 16, 2), 256, 0, stream>>>(x, w0, w1, preT);
    gate_s0<<<S0_BLOCKS + (unsigned)((size_t)N * N * 4 / 256), 256, 0, stream>>>(
        ef, we, be, sup, preT, G, partial0);
    gemm_g_out<<<512, 512, 0, stream>>>(G, preT, partial0, b, out);
}

// Round 16
// 132.654 us; speedup vs baseline: 1.0674x; 1.0449x over previous
//
#include <hip/hip_runtime.h>
#include <math.h>

#define N 2048
#define F 128
#define O 128
#define E 16

typedef __attribute__((ext_vector_type(8))) short          shortx8;
typedef __attribute__((ext_vector_type(8))) unsigned short u16x8;
typedef __attribute__((ext_vector_type(4))) unsigned short u16x4;
typedef __attribute__((ext_vector_type(4))) float          floatx4;

static __device__ __forceinline__ unsigned short f2bf(float f) {
    unsigned int u = __float_as_uint(f);
    unsigned int r = (u + 0x7FFFu + ((u >> 16) & 1u)) >> 16;
    return (unsigned short)r;
}

// ---------------- Kernel 1: FUSED pre_t + gate (block specialization) ---------------
// blocks 0..255:      preT[b][o][n] = (x @ w_b)[n][o]  (LDS-free, w from L2)
// blocks 256..65791:  R10-form gate -> G  (4 lanes per pair)
// __launch_bounds__(256, 8): hard 64-VGPR cap so gate keeps 8 waves/SIMD.
#define PRE_BLOCKS 256

__global__ __launch_bounds__(256, 8)
void pre_gate(const float* __restrict__ x,
              const float* __restrict__ w0,
              const float* __restrict__ w1,
              const float* __restrict__ ef,
              const float* __restrict__ we,
              const float* __restrict__ be,
              const float* __restrict__ sup1,
              unsigned short* __restrict__ preT,
              unsigned short* __restrict__ G) {
    const int bx = blockIdx.x;
    const int t  = threadIdx.x;

    if (bx < PRE_BLOCKS) {
        // ---- pre_t path: block (nblk, b); 4 waves cover 128 cols ----
        const int nblk = bx & 127;
        const int b    = bx >> 7;
        const int n0   = nblk * 16;
        const float* __restrict__ wsrc = b ? w1 : w0;

        const int lane = t & 63;
        const int wv   = t >> 6;        // 0..3: 32-col group
        const int row  = lane & 15;
        const int kg   = lane >> 4;
        const int col0 = wv * 32 + row;

        floatx4 acc0 = {0.f, 0.f, 0.f, 0.f};
        floatx4 acc1 = {0.f, 0.f, 0.f, 0.f};

#pragma unroll
        for (int kk = 0; kk < 4; ++kk) {
            // A fragment: x rows, k-contiguous
            const float* xp = x + (size_t)(n0 + row) * F + kk * 32 + kg * 8;
            const float4 f0 = *(const float4*)(xp);
            const float4 f1 = *(const float4*)(xp + 4);
            shortx8 a;
            a[0] = (short)f2bf(f0.x); a[1] = (short)f2bf(f0.y);
            a[2] = (short)f2bf(f0.z); a[3] = (short)f2bf(f0.w);
            a[4] = (short)f2bf(f1.x); a[5] = (short)f2bf(f1.y);
            a[6] = (short)f2bf(f1.z); a[7] = (short)f2bf(f1.w);
            // B fragments: w[k][col], k strided by O (w is 64KB, L2-resident)
            const float* wp = wsrc + (size_t)(kk * 32 + kg * 8) * O;
            shortx8 bA, bB;
#pragma unroll
            for (int j = 0; j < 8; ++j) {
                bA[j] = (short)f2bf(wp[(size_t)j * O + col0]);
                bB[j] = (short)f2bf(wp[(size_t)j * O + col0 + 16]);
            }
            acc0 = __builtin_amdgcn_mfma_f32_16x16x32_bf16(a, bA, acc0, 0, 0, 0);
            acc1 = __builtin_amdgcn_mfma_f32_16x16x32_bf16(a, bB, acc1, 0, 0, 0);
        }

        // C/D: col = lane&15, row = kg*4 + j -> preT[b][col][n0 + kg*4 + j]
        const int prow = kg * 4;
        u16x4 s0, s1;
#pragma unroll
        for (int j = 0; j < 4; ++j) { s0[j] = f2bf(acc0[j]); s1[j] = f2bf(acc1[j]); }
        *(u16x4*)(preT + ((size_t)b * O + col0) * N + n0 + prow)      = s0;
        *(u16x4*)(preT + ((size_t)b * O + col0 + 16) * N + n0 + prow) = s1;
    } else {
        // ---- gate path (R10 form, byte-identical math) ----
        const size_t tid  = (size_t)(bx - PRE_BLOCKS) * 256 + t;
        const size_t pair = tid >> 2;
        const int    sub  = t & 3;
        const float4 e4 = ((const float4*)ef)[pair * 4 + sub];
        const float4 w4 = ((const float4*)we)[pair * 4 + sub];
        float v = e4.x * w4.x + e4.y * w4.y + e4.z * w4.z + e4.w * w4.w;
        v += __shfl_xor(v, 1);
        v += __shfl_xor(v, 2);
        if (sub == 0) {
            const float tt = v + be[pair];
            const float g  = (1.f / (1.f + __expf(-tt))) * sup1[pair];
            G[pair] = f2bf(g);
        }
    }
}

// ---------------- Kernel 2: dual GEMM, 8-wave in-block split-K (R10 form) -----------
__global__ __launch_bounds__(512, 4)
void gemm_direct(const float* __restrict__ S0,
                 const unsigned short* __restrict__ G,
                 const unsigned short* __restrict__ preT,
                 const float* __restrict__ bias,
                 float* __restrict__ out) {
    __shared__ float red[8][16][36];

    const int bx   = blockIdx.x;
    const int orig = (bx & 7) * 64 + (bx >> 3);  // group 4 col-blocks per XCD
    const int rb   = orig >> 2;                  // 0..127
    const int cg   = orig & 3;                   // 0..3
    const int n0   = rb * 16;

    const int t    = threadIdx.x;
    const int lane = t & 63;
    const int wv   = t >> 6;                     // 0..7
    const int m_b  = wv * 256;
    const int row  = lane & 15;
    const int kg   = lane >> 4;
    const int col0 = cg * 32 + row;

    const float*          aS = S0   + (size_t)(n0 + row) * N + m_b + kg * 8;
    const unsigned short* aG = G    + (size_t)(n0 + row) * N + m_b + kg * 8;
    const unsigned short* b0 = preT + (size_t)col0 * N        + m_b + kg * 8;
    const unsigned short* b1 = b0 + (size_t)16 * N;
    const unsigned short* c0 = b0 + (size_t)O * N;   // preT[1]
    const unsigned short* c1 = b1 + (size_t)O * N;

    floatx4 acc0 = {0.f, 0.f, 0.f, 0.f};
    floatx4 acc1 = {0.f, 0.f, 0.f, 0.f};

#pragma unroll 2
    for (int s = 0; s < 8; ++s) {
        const int mo = s * 32;
        const float4 f0 = *(const float4*)(aS + mo);
        const float4 f1 = *(const float4*)(aS + mo + 4);
        const shortx8 a_g = *(const shortx8*)(aG + mo);
        const shortx8 b00 = *(const shortx8*)(b0 + mo);
        const shortx8 b01 = *(const shortx8*)(b1 + mo);
        const shortx8 b10 = *(const shortx8*)(c0 + mo);
        const shortx8 b11 = *(const shortx8*)(c1 + mo);
        shortx8 a_s;
        a_s[0] = (short)f2bf(f0.x); a_s[1] = (short)f2bf(f0.y);
        a_s[2] = (short)f2bf(f0.z); a_s[3] = (short)f2bf(f0.w);
        a_s[4] = (short)f2bf(f1.x); a_s[5] = (short)f2bf(f1.y);
        a_s[6] = (short)f2bf(f1.z); a_s[7] = (short)f2bf(f1.w);
        acc0 = __builtin_amdgcn_mfma_f32_16x16x32_bf16(a_s, b00, acc0, 0, 0, 0);
        acc0 = __builtin_amdgcn_mfma_f32_16x16x32_bf16(a_g, b10, acc0, 0, 0, 0);
        acc1 = __builtin_amdgcn_mfma_f32_16x16x32_bf16(a_s, b01, acc1, 0, 0, 0);
        acc1 = __builtin_amdgcn_mfma_f32_16x16x32_bf16(a_g, b11, acc1, 0, 0, 0);
    }

    // stash per-wave acc in LDS: C/D col = lane&15, row = kg*4 + j
    const int prow = kg * 4;
#pragma unroll
    for (int j = 0; j < 4; ++j) {
        red[wv][prow + j][row]      = acc0[j];
        red[wv][prow + j][16 + row] = acc1[j];
    }
    __syncthreads();

    // first 256 threads: one row r, two cols c,c+1; sum over 8 waves
    if (t < 256) {
        const int r = t >> 4;
        const int c = (t & 15) * 2;
        float v0 = 0.f, v1 = 0.f;
#pragma unroll
        for (int w = 0; w < 8; ++w) {
            v0 += red[w][r][c];
            v1 += red[w][r][c + 1];
        }
        v0 = fmaxf(v0 + bias[cg * 32 + c],     0.f);
        v1 = fmaxf(v1 + bias[cg * 32 + c + 1], 0.f);
        float2 o2; o2.x = v0; o2.y = v1;
        *(float2*)(out + (size_t)(n0 + r) * O + cg * 32 + c) = o2;
    }
}

extern "C" void kernel_launch(void* const* d_in, const int* in_sizes, int n_in,
                              void* d_out, int out_size, void* d_ws, size_t ws_size,
                              hipStream_t stream) {
    const float* x   = (const float*)d_in[0];   // [N,F]
    const float* sup = (const float*)d_in[1];   // [2,N,N]
    const float* ef  = (const float*)d_in[2];   // [N,N,E]
    const float* we  = (const float*)d_in[3];   // [N,N,E]
    const float* be  = (const float*)d_in[4];   // [N,N]
    const float* w0  = (const float*)d_in[5];   // [F,O]
    const float* w1  = (const float*)d_in[6];   // [F,O]
    const float* b   = (const float*)d_in[7];   // [O]
    float* out = (float*)d_out;

    unsigned short* preT = (unsigned short*)d_ws;    // [2][O][N] bf16, 1 MB
    unsigned short* G    = preT + 2 * (size_t)N * O; // [N][N]   bf16, 8.4 MB

    pre_gate<<<PRE_BLOCKS + (unsigned)((size_t)N * N * 4 / 256), 256, 0, stream>>>(
        x, w0, w1, ef, we, be, sup + (size_t)N * N, preT, G);
    gemm_direct<<<512, 512, 0, stream>>>(sup, G, preT, b, out);
}